// Round 8
// baseline (227.331 us; speedup 1.0000x reference)
//
#include <hip/hip_runtime.h>

// ---------------------------------------------------------------------------
// QCNN classifier: whole circuit == fixed 1024x1024 unitary U(weights).
// out[b,0] = 1 - 2*sum_{bit9(s)=1} |(U x_b)_s|^2 / ||x_b||^2   (qubit 0)
// out[b,1] = 1 - 2*sum_{bit7(s)=1} |(U x_b)_s|^2 / ||x_b||^2   (qubit 2)
// Only 768 of 1024 states needed (bit9|bit7) -> N=1536 GEMM (51.5 GF).
// R8: prep split into sim_U (512 blocks x 2 cols -> 2 blocks/CU, in-place,
// s_load gates, f16x2 XCD-swizzled stores) + zero-LDS norm_conv, so rocprof
// attributes the hidden ~70us. gemm/finalize unchanged.
// ---------------------------------------------------------------------------

typedef _Float16 f16;
typedef f16 f16x8 __attribute__((ext_vector_type(8)));
typedef f16 f16x4 __attribute__((ext_vector_type(4)));
typedef f16 f16x2 __attribute__((ext_vector_type(2)));
typedef float f32x4 __attribute__((ext_vector_type(4)));

__device__ inline float2 cmul(float2 a, float2 b) {
    return make_float2(a.x * b.x - a.y * b.y, a.x * b.y + a.y * b.x);
}
__device__ inline float2 cadd(float2 a, float2 b) {
    return make_float2(a.x + b.x, a.y + b.y);
}

struct M2 { float2 m[4]; };

__device__ inline M2 m2_u3(float t, float p, float d) {
    float c = cosf(0.5f * t), s = sinf(0.5f * t);
    float2 ep = make_float2(cosf(p), sinf(p));
    float2 ed = make_float2(cosf(d), sinf(d));
    M2 U;
    U.m[0] = make_float2(c, 0.f);
    U.m[1] = make_float2(-ed.x * s, -ed.y * s);
    U.m[2] = make_float2(ep.x * s, ep.y * s);
    float2 epd = cmul(ep, ed);
    U.m[3] = make_float2(epd.x * c, epd.y * c);
    return U;
}
__device__ inline M2 m2_ry(float t) {
    float c = cosf(0.5f * t), s = sinf(0.5f * t);
    M2 U;
    U.m[0] = make_float2(c, 0.f);  U.m[1] = make_float2(-s, 0.f);
    U.m[2] = make_float2(s, 0.f);  U.m[3] = make_float2(c, 0.f);
    return U;
}
__device__ inline M2 m2_rz(float t) {
    float c = cosf(0.5f * t), s = sinf(0.5f * t);
    M2 U;
    U.m[0] = make_float2(c, -s); U.m[1] = make_float2(0.f, 0.f);
    U.m[2] = make_float2(0.f, 0.f); U.m[3] = make_float2(c, s);
    return U;
}
__device__ inline M2 m2_rx(float t) {
    float c = cosf(0.5f * t), s = sinf(0.5f * t);
    M2 U;
    U.m[0] = make_float2(c, 0.f);   U.m[1] = make_float2(0.f, -s);
    U.m[2] = make_float2(0.f, -s);  U.m[3] = make_float2(c, 0.f);
    return U;
}

// apply 2x2 complex matrix to an amplitude pair
__device__ inline void ap2x2(float2& x, float2& y, const M2& U) {
    float2 nx = cadd(cmul(U.m[0], x), cmul(U.m[1], y));
    float2 ny = cadd(cmul(U.m[2], x), cmul(U.m[3], y));
    x = nx; y = ny;
}
// 4-vector indexed by (2a+b). apA: U on a (pairs 0-2, 1-3). apB: U on b (0-1, 2-3).
__device__ inline void apA(float2 v[4], const M2& U) { ap2x2(v[0], v[2], U); ap2x2(v[1], v[3], U); }
__device__ inline void apB(float2 v[4], const M2& U) { ap2x2(v[0], v[1], U); ap2x2(v[2], v[3], U); }
__device__ inline void swapv(float2& a, float2& b) { float2 t = a; a = b; b = t; }

// column c of the conv block: propagate e_c through the 10 elementary steps
__device__ inline void conv_col(const float* w, float2 v[4]) {
    apA(v, m2_u3(w[0], w[1], w[2]));
    apB(v, m2_u3(w[3], w[4], w[5]));
    swapv(v[2], v[3]);                    // cnot (control=a)
    apA(v, m2_ry(w[6]));
    apB(v, m2_rz(w[7]));
    swapv(v[1], v[3]);                    // cnot (control=b)
    apA(v, m2_ry(w[8]));
    swapv(v[2], v[3]);                    // cnot (control=a)
    apA(v, m2_u3(w[9], w[10], w[11]));
    apB(v, m2_u3(w[12], w[13], w[14]));
}
__device__ inline void pool_col(const float* p, float2 v[4]) {
    {   // crz(p0): diag(1,1,e^{-ip0/2},e^{+ip0/2})
        float c = cosf(0.5f * p[0]), s = sinf(0.5f * p[0]);
        v[2] = cmul(v[2], make_float2(c, -s));
        v[3] = cmul(v[3], make_float2(c, s));
    }
    swapv(v[0], v[2]); swapv(v[1], v[3]); // X on a
    {   // crx(p1) on (v2,v3)
        M2 U = m2_rx(p[1]);
        ap2x2(v[2], v[3], U);
    }
}

// One thread per (gate, column). Writes gp (bit positions) + gm (matrices)
// to GLOBAL memory so the sim can read them with uniform s_loads.
__global__ void build_gates(const float* wc1, const float* wc2,
                            const float* wp1, const float* wp2,
                            const float* wfc, int2* gp, float2* gm) {
    const int t = threadIdx.x;
    const int n = t >> 2, c = t & 3;
    if (blockIdx.x != 0 || n >= 27) return;

    float2 v[4];
    for (int i = 0; i < 4; i++) v[i] = make_float2(0.f, 0.f);
    v[c] = make_float2(1.f, 0.f);

    int a, b;
    if (n < 5)        { int i = 2*n;       a = i;   b = i+1; conv_col(wc1 + 15*i, v); }
    else if (n < 9)   { int i = 2*(n-5)+1; a = i;   b = i+1; conv_col(wc1 + 15*i, v); }
    else if (n == 9)  { a = 0; b = 9;      conv_col(wc1 + 105, v); }
    else if (n < 15)  { int idx = n-10, i = 2*idx; a = i+1; b = i; pool_col(wp1 + 2*idx, v); }
    else if (n < 19)  { int idx = n-15, i = 2*idx; a = i; b = i+2; conv_col(wc2 + 15*idx, v); }
    else if (n == 19) { a = 2; b = 0;      pool_col(wp2 + 0, v); }
    else if (n == 20) { a = 6; b = 4;      pool_col(wp2 + 2, v); }
    else if (n <= 23) { // CNOTs (control = a)
        a = (n == 21) ? 0 : (n == 22) ? 2 : 4;
        b = (n == 23) ? 0 : 4;
        swapv(v[2], v[3]);
    } else {            // RX on qubit a
        a = (n == 24) ? 0 : (n == 25) ? 2 : 4;
        b = a + 1;
        apA(v, m2_rx(wfc[n - 24]));
    }
    if (c == 0) gp[n] = make_int2(9 - a, 9 - b);   // qubit q -> bit (9-q)
    for (int i = 0; i < 4; i++) gm[n * 16 + i * 4 + c] = v[i];
}

#define SIM_BLOCKS 512     // 2 columns each -> 2 blocks/CU

// Per-basis-state columns of U: 2 columns/block simulated in LDS (in-place,
// 1 barrier/gate; gate matrices via uniform s_load from gm), f16x2 stores
// into BTh [n'][1024 k]. XCD-group swizzle: XCD x (= sb%8) owns t range
// [128x, 128x+128) so the 64-B BTh lines merge within one L2.
__global__ __launch_bounds__(256) void sim_U(const int2* __restrict__ gp,
                                             const float2* __restrict__ gm,
                                             f16* __restrict__ BTh) {
    __shared__ float2 st[2][1025];   // [col][state], +1 pad
    const int sb = blockIdx.x;
    const int t0 = (sb & 7) * 128 + (sb >> 3) * 2;   // XCD-group swizzle

    for (int i = threadIdx.x; i < 1024; i += 256) {
        st[0][i] = make_float2((i == t0) ? 1.f : 0.f, 0.f);
        st[1][i] = make_float2((i == t0 + 1) ? 1.f : 0.f, 0.f);
    }
    __syncthreads();

    for (int g = 0; g < 27; g++) {
        const int2 p = gp[g];            // uniform -> s_load
        float2 m[16];
#pragma unroll
        for (int i = 0; i < 16; i++) m[i] = gm[g * 16 + i];   // uniform -> s_load
        const int p1 = p.x, p2 = p.y;
        const int lo = min(p1, p2), hi = max(p1, p2);
        const int q = threadIdx.x;
        const int m1 = (1 << lo) - 1;
        int tt = (q & m1) | ((q & ~m1) << 1);
        const int m2m = (1 << hi) - 1;
        const int i0 = (tt & m2m) | ((tt & ~m2m) << 1);
        int idx[4];
        for (int ga = 0; ga < 2; ga++)
            for (int gb = 0; gb < 2; gb++)
                idx[2 * ga + gb] = i0 | (ga << p1) | (gb << p2);
#pragma unroll
        for (int c = 0; c < 2; c++) {
            float2 v[4];
#pragma unroll
            for (int i = 0; i < 4; i++) v[i] = st[c][idx[i]];
#pragma unroll
            for (int i = 0; i < 4; i++) {
                float2 s = make_float2(0.f, 0.f);
#pragma unroll
                for (int j = 0; j < 4; j++) s = cadd(s, cmul(m[i * 4 + j], v[j]));
                st[c][idx[i]] = s;       // in-place: quad is thread-private
            }
        }
        __syncthreads();
    }

    // --- f16x2 store into BTh [n'][1024] at columns t0, t0+1 ---
    // n' < 768 = Re, else Im; n' % 768 = grp*256 + pos,
    // grp: (b9,b7)=(1,0)->0, (1,1)->1, (0,1)->2; pos = bit8(s)*128 | (s&127).
    for (int s = threadIdx.x; s < 1024; s += 256) {
        const int b9 = (s >> 9) & 1, b7 = (s >> 7) & 1;
        if (b9 | b7) {
            const int grp = b9 ? b7 : 2;
            const int pos = (((s >> 8) & 1) << 7) | (s & 127);
            const int np = grp * 256 + pos;
            f16x2 re, im;
#pragma unroll
            for (int c = 0; c < 2; c++) {
                re[c] = (f16)st[c][s].x;
                im[c] = (f16)st[c][s].y;
            }
            *(f16x2*)(BTh + (size_t)np * 1024 + t0) = re;
            *(f16x2*)(BTh + (size_t)(np + 768) * 1024 + t0) = im;
        }
    }
}

// Row norms + fp32->f16 conversion of X. Zero LDS, wave-per-row, 8 rows/block.
__global__ __launch_bounds__(256) void norm_conv(const float* __restrict__ X,
                                                 float* __restrict__ nrm2,
                                                 f16* __restrict__ Xh) {
    const int w = threadIdx.x >> 6, l = threadIdx.x & 63;
#pragma unroll
    for (int r = 0; r < 2; r++) {
        const int row = blockIdx.x * 8 + w * 2 + r;
        const float4* xr = (const float4*)(X + (size_t)row * 1024);
        float s = 0.f;
#pragma unroll
        for (int ch = 0; ch < 4; ch++) {
            float4 v = xr[ch * 64 + l];
            f16x4 h;
            h[0] = (f16)v.x; h[1] = (f16)v.y; h[2] = (f16)v.z; h[3] = (f16)v.w;
            *(f16x4*)(Xh + (size_t)row * 1024 + (ch * 64 + l) * 4) = h;
            s += v.x * v.x + v.y * v.y + v.z * v.z + v.w * v.w;
        }
#pragma unroll
        for (int off = 32; off >= 1; off >>= 1) s += __shfl_xor(s, off, 64);
        if (l == 0) nrm2[row] = s;
    }
}

__device__ __forceinline__ void glds16(const void* g, void* l) {
    __builtin_amdgcn_global_load_lds(
        (const __attribute__((address_space(1))) void*)g,
        (__attribute__((address_space(3))) void*)l, 16, 0, 0);
}

// Y = Xh @ BTh^T fused with masked-square reduction.
// A: 16384x1024 f16. Bt: 1536x1024 f16 (N x K). 128x128 tile, BK=32, 4 waves,
// each wave 64x64 via 4x4 of 16x16x32 MFMA. LDS XOR chunk-swizzle (R2-verified).
// partial[by][row][k] = per-block sums of |y|^2 over cols with weight_k(n)=1.
__global__ __launch_bounds__(256) void gemm_mfma(const f16* __restrict__ A,
                                                 const f16* __restrict__ Bt,
                                                 float* __restrict__ partial) {
    __shared__ char Ash[8192];
    __shared__ char Bsh[8192];
    __shared__ float pLDS[128][2][2];
    const int tid = threadIdx.x;
    const int l = tid & 63, w = tid >> 6;
    const int wr = w >> 1, wc = w & 1;
    const int row0 = blockIdx.x * 128, col0 = blockIdx.y * 128;

    const int mrow = l >> 2;
    const int kc = (l & 3) ^ ((l >> 3) & 3);
    const f16* aS0 = A  + (size_t)(row0 + 32 * w + mrow) * 1024 + kc * 8;
    const f16* aS1 = aS0 + 16 * 1024;
    const f16* bS0 = Bt + (size_t)(col0 + 32 * w + mrow) * 1024 + kc * 8;
    const f16* bS1 = bS0 + 16 * 1024;
    char* aD0 = Ash + 2048 * w;
    char* aD1 = aD0 + 1024;
    char* bD0 = Bsh + 2048 * w;
    char* bD1 = bD0 + 1024;

    int aOff[4], bOff[4];
#pragma unroll
    for (int i = 0; i < 4; i++) {
        int m = wr * 64 + i * 16 + (l & 15);
        aOff[i] = m * 64 + (((l >> 4) ^ ((m >> 1) & 3)) << 4);
        int n = wc * 64 + i * 16 + (l & 15);
        bOff[i] = n * 64 + (((l >> 4) ^ ((n >> 1) & 3)) << 4);
    }

    f32x4 acc[4][4];
    const f32x4 z = {0.f, 0.f, 0.f, 0.f};
#pragma unroll
    for (int i = 0; i < 4; i++)
#pragma unroll
        for (int j = 0; j < 4; j++) acc[i][j] = z;

    for (int k0 = 0; k0 < 1024; k0 += 32) {
        glds16(aS0 + k0, aD0);
        glds16(aS1 + k0, aD1);
        glds16(bS0 + k0, bD0);
        glds16(bS1 + k0, bD1);
        __syncthreads();
        f16x8 af[4], bf[4];
#pragma unroll
        for (int i = 0; i < 4; i++) {
            af[i] = *(const f16x8*)(Ash + aOff[i]);
            bf[i] = *(const f16x8*)(Bsh + bOff[i]);
        }
#pragma unroll
        for (int mi = 0; mi < 4; mi++)
#pragma unroll
            for (int ni = 0; ni < 4; ni++)
                acc[mi][ni] = __builtin_amdgcn_mfma_f32_16x16x32_f16(
                    af[mi], bf[ni], acc[mi][ni], 0, 0, 0);
        __syncthreads();
    }

    // fused epilogue: group-weighted squares, reduce cols
    float c0[4][4], c1[4][4];   // [mi][reg-row]
#pragma unroll
    for (int mi = 0; mi < 4; mi++)
#pragma unroll
        for (int rr = 0; rr < 4; rr++) { c0[mi][rr] = 0.f; c1[mi][rr] = 0.f; }
#pragma unroll
    for (int ni = 0; ni < 4; ni++) {
        const int n_glob = col0 + wc * 64 + ni * 16 + (l & 15);
        const int nm = (n_glob >= 768) ? n_glob - 768 : n_glob;
        const int grp = nm >> 8;                       // 0: b9 only, 1: both, 2: b7 only
        const float w0 = (grp <= 1) ? 1.f : 0.f;
        const float w1 = (grp >= 1) ? 1.f : 0.f;
#pragma unroll
        for (int mi = 0; mi < 4; mi++)
#pragma unroll
            for (int rr = 0; rr < 4; rr++) {
                const float y = acc[mi][ni][rr];
                const float y2 = y * y;
                c0[mi][rr] += w0 * y2;
                c1[mi][rr] += w1 * y2;
            }
    }
#pragma unroll
    for (int off = 1; off < 16; off <<= 1)
#pragma unroll
        for (int mi = 0; mi < 4; mi++)
#pragma unroll
            for (int rr = 0; rr < 4; rr++) {
                c0[mi][rr] += __shfl_xor(c0[mi][rr], off, 64);
                c1[mi][rr] += __shfl_xor(c1[mi][rr], off, 64);
            }
    if ((l & 15) == 0) {
        const int q = l >> 4;
#pragma unroll
        for (int mi = 0; mi < 4; mi++)
#pragma unroll
            for (int rr = 0; rr < 4; rr++) {
                const int r = wr * 64 + mi * 16 + q * 4 + rr;
                pLDS[r][wc][0] = c0[mi][rr];
                pLDS[r][wc][1] = c1[mi][rr];
            }
    }
    __syncthreads();
    {
        const int r = tid >> 1, k = tid & 1;
        const float v = pLDS[r][0][k] + pLDS[r][1][k];
        partial[((size_t)blockIdx.y * 16384 + row0 + r) * 2 + k] = v;
    }
}

__global__ __launch_bounds__(256) void finalize(const float* __restrict__ partial,
                                                const float* __restrict__ nrm2,
                                                float* __restrict__ out) {
    const int i = blockIdx.x * 256 + threadIdx.x;   // 32768
    const int b = i >> 1, k = i & 1;
    float s = 0.f;
#pragma unroll
    for (int ny = 0; ny < 12; ny++) s += partial[((size_t)ny * 16384 + b) * 2 + k];
    out[i] = 1.f - 2.f * s / nrm2[b];
}

extern "C" void kernel_launch(void* const* d_in, const int* in_sizes, int n_in,
                              void* d_out, int out_size, void* d_ws, size_t ws_size,
                              hipStream_t stream) {
    const float* x   = (const float*)d_in[0];   // 16384 x 1024
    const float* wc1 = (const float*)d_in[1];   // 10 x 15
    const float* wc2 = (const float*)d_in[2];   // 4 x 15
    const float* wp1 = (const float*)d_in[3];   // 5 x 2
    const float* wp2 = (const float*)d_in[4];   // 2 x 2
    const float* wfc = (const float*)d_in[5];   // 3
    float* out = (float*)d_out;                 // 16384 x 2

    uintptr_t wsp = (uintptr_t)d_ws;
    int2*   gp     = (int2*)wsp;                                   // 216 B
    float2* gm     = (float2*)(wsp + 1024);                        // 3.4 KB
    f16*    BTh    = (f16*)(wsp + 8192);                           // 3 MB (1536x1024)
    f16*    Xh     = (f16*)(wsp + 8192 + (3u << 20));              // 32 MB
    float*  nrm2   = (float*)(wsp + 8192 + (35u << 20));           // 64 KB
    float*  partial= (float*)(wsp + 8192 + (35u << 20) + 65536);   // 1.5 MB (12x16384x2)

    build_gates<<<1, 128, 0, stream>>>(wc1, wc2, wp1, wp2, wfc, gp, gm);
    sim_U<<<SIM_BLOCKS, 256, 0, stream>>>(gp, gm, BTh);
    norm_conv<<<2048, 256, 0, stream>>>(x, nrm2, Xh);
    gemm_mfma<<<dim3(128, 12), 256, 0, stream>>>(Xh, BTh, partial);
    finalize<<<128, 256, 0, stream>>>(partial, nrm2, out);
}

// Round 9
// 215.780 us; speedup vs baseline: 1.0535x; 1.0535x over previous
//
#include <hip/hip_runtime.h>

// ---------------------------------------------------------------------------
// QCNN classifier: whole circuit == fixed 1024x1024 unitary U(weights).
// out[b,0] = 1 - 2*sum_{bit9(s)=1} |(U x_b)_s|^2 / ||x_b||^2   (qubit 0)
// out[b,1] = 1 - 2*sum_{bit7(s)=1} |(U x_b)_s|^2 / ||x_b||^2   (qubit 2)
// Only 768 of 1024 states needed (bit9|bit7) -> N=1536 GEMM (51.5 GF).
// R9: 5 -> 3 kernels. prep = sim_U(512x2cols, s_load gates) + norm_conv +
// out=1 init. gemm epilogue atomically accumulates -2*c/nrm2 into out
// (finalize + partial buffer removed). ~5-10us/boundary evidence: R7->R8
// split of one kernel cost +7us at identical kernel durations.
// ---------------------------------------------------------------------------

typedef _Float16 f16;
typedef f16 f16x8 __attribute__((ext_vector_type(8)));
typedef f16 f16x4 __attribute__((ext_vector_type(4)));
typedef f16 f16x2 __attribute__((ext_vector_type(2)));
typedef float f32x4 __attribute__((ext_vector_type(4)));

__device__ inline float2 cmul(float2 a, float2 b) {
    return make_float2(a.x * b.x - a.y * b.y, a.x * b.y + a.y * b.x);
}
__device__ inline float2 cadd(float2 a, float2 b) {
    return make_float2(a.x + b.x, a.y + b.y);
}

struct M2 { float2 m[4]; };

__device__ inline M2 m2_u3(float t, float p, float d) {
    float c = cosf(0.5f * t), s = sinf(0.5f * t);
    float2 ep = make_float2(cosf(p), sinf(p));
    float2 ed = make_float2(cosf(d), sinf(d));
    M2 U;
    U.m[0] = make_float2(c, 0.f);
    U.m[1] = make_float2(-ed.x * s, -ed.y * s);
    U.m[2] = make_float2(ep.x * s, ep.y * s);
    float2 epd = cmul(ep, ed);
    U.m[3] = make_float2(epd.x * c, epd.y * c);
    return U;
}
__device__ inline M2 m2_ry(float t) {
    float c = cosf(0.5f * t), s = sinf(0.5f * t);
    M2 U;
    U.m[0] = make_float2(c, 0.f);  U.m[1] = make_float2(-s, 0.f);
    U.m[2] = make_float2(s, 0.f);  U.m[3] = make_float2(c, 0.f);
    return U;
}
__device__ inline M2 m2_rz(float t) {
    float c = cosf(0.5f * t), s = sinf(0.5f * t);
    M2 U;
    U.m[0] = make_float2(c, -s); U.m[1] = make_float2(0.f, 0.f);
    U.m[2] = make_float2(0.f, 0.f); U.m[3] = make_float2(c, s);
    return U;
}
__device__ inline M2 m2_rx(float t) {
    float c = cosf(0.5f * t), s = sinf(0.5f * t);
    M2 U;
    U.m[0] = make_float2(c, 0.f);   U.m[1] = make_float2(0.f, -s);
    U.m[2] = make_float2(0.f, -s);  U.m[3] = make_float2(c, 0.f);
    return U;
}

// apply 2x2 complex matrix to an amplitude pair
__device__ inline void ap2x2(float2& x, float2& y, const M2& U) {
    float2 nx = cadd(cmul(U.m[0], x), cmul(U.m[1], y));
    float2 ny = cadd(cmul(U.m[2], x), cmul(U.m[3], y));
    x = nx; y = ny;
}
// 4-vector indexed by (2a+b). apA: U on a (pairs 0-2, 1-3). apB: U on b (0-1, 2-3).
__device__ inline void apA(float2 v[4], const M2& U) { ap2x2(v[0], v[2], U); ap2x2(v[1], v[3], U); }
__device__ inline void apB(float2 v[4], const M2& U) { ap2x2(v[0], v[1], U); ap2x2(v[2], v[3], U); }
__device__ inline void swapv(float2& a, float2& b) { float2 t = a; a = b; b = t; }

// column c of the conv block: propagate e_c through the 10 elementary steps
__device__ inline void conv_col(const float* w, float2 v[4]) {
    apA(v, m2_u3(w[0], w[1], w[2]));
    apB(v, m2_u3(w[3], w[4], w[5]));
    swapv(v[2], v[3]);                    // cnot (control=a)
    apA(v, m2_ry(w[6]));
    apB(v, m2_rz(w[7]));
    swapv(v[1], v[3]);                    // cnot (control=b)
    apA(v, m2_ry(w[8]));
    swapv(v[2], v[3]);                    // cnot (control=a)
    apA(v, m2_u3(w[9], w[10], w[11]));
    apB(v, m2_u3(w[12], w[13], w[14]));
}
__device__ inline void pool_col(const float* p, float2 v[4]) {
    {   // crz(p0): diag(1,1,e^{-ip0/2},e^{+ip0/2})
        float c = cosf(0.5f * p[0]), s = sinf(0.5f * p[0]);
        v[2] = cmul(v[2], make_float2(c, -s));
        v[3] = cmul(v[3], make_float2(c, s));
    }
    swapv(v[0], v[2]); swapv(v[1], v[3]); // X on a
    {   // crx(p1) on (v2,v3)
        M2 U = m2_rx(p[1]);
        ap2x2(v[2], v[3], U);
    }
}

// One thread per (gate, column). Writes gp (bit positions) + gm (matrices)
// to GLOBAL memory so the sim can read them with uniform s_loads.
__global__ void build_gates(const float* wc1, const float* wc2,
                            const float* wp1, const float* wp2,
                            const float* wfc, int2* gp, float2* gm) {
    const int t = threadIdx.x;
    const int n = t >> 2, c = t & 3;
    if (blockIdx.x != 0 || n >= 27) return;

    float2 v[4];
    for (int i = 0; i < 4; i++) v[i] = make_float2(0.f, 0.f);
    v[c] = make_float2(1.f, 0.f);

    int a, b;
    if (n < 5)        { int i = 2*n;       a = i;   b = i+1; conv_col(wc1 + 15*i, v); }
    else if (n < 9)   { int i = 2*(n-5)+1; a = i;   b = i+1; conv_col(wc1 + 15*i, v); }
    else if (n == 9)  { a = 0; b = 9;      conv_col(wc1 + 105, v); }
    else if (n < 15)  { int idx = n-10, i = 2*idx; a = i+1; b = i; pool_col(wp1 + 2*idx, v); }
    else if (n < 19)  { int idx = n-15, i = 2*idx; a = i; b = i+2; conv_col(wc2 + 15*idx, v); }
    else if (n == 19) { a = 2; b = 0;      pool_col(wp2 + 0, v); }
    else if (n == 20) { a = 6; b = 4;      pool_col(wp2 + 2, v); }
    else if (n <= 23) { // CNOTs (control = a)
        a = (n == 21) ? 0 : (n == 22) ? 2 : 4;
        b = (n == 23) ? 0 : 4;
        swapv(v[2], v[3]);
    } else {            // RX on qubit a
        a = (n == 24) ? 0 : (n == 25) ? 2 : 4;
        b = a + 1;
        apA(v, m2_rx(wfc[n - 24]));
    }
    if (c == 0) gp[n] = make_int2(9 - a, 9 - b);   // qubit q -> bit (9-q)
    for (int i = 0; i < 4; i++) gm[n * 16 + i * 4 + c] = v[i];
}

#define SIM_BLOCKS 512     // 2 columns each, dispatched FIRST
#define NORM_BLOCKS 2048   // 8 rows/block

// Fused prep. Blocks [0, SIM_BLOCKS): 2 U-columns simulated in LDS (in-place,
// 1 barrier/gate; gate matrices via uniform s_load from gm), f16x2 stores into
// BTh [n'][1024 k] with XCD-group t-swizzle (XCD x owns t range [128x,128x+128)).
// Blocks [SIM_BLOCKS, +NORM_BLOCKS): row norms + fp32->f16 X conversion
// (wave-per-row, no LDS use) + out = 1.0 init for its 8 rows.
__global__ __launch_bounds__(256) void prep(const float* __restrict__ X,
                                            const int2* __restrict__ gp,
                                            const float2* __restrict__ gm,
                                            float* __restrict__ nrm2,
                                            f16* __restrict__ Xh,
                                            f16* __restrict__ BTh,
                                            float* __restrict__ out) {
    __shared__ float2 st[2][1025];   // [col][state], +1 pad
    const int bid = blockIdx.x;

    if (bid >= SIM_BLOCKS) {
        const int nb = bid - SIM_BLOCKS;
        const int w = threadIdx.x >> 6, l = threadIdx.x & 63;
        if (threadIdx.x < 16) out[nb * 16 + threadIdx.x] = 1.0f;
#pragma unroll
        for (int r = 0; r < 2; r++) {
            const int row = nb * 8 + w * 2 + r;
            const float4* xr = (const float4*)(X + (size_t)row * 1024);
            float s = 0.f;
#pragma unroll
            for (int ch = 0; ch < 4; ch++) {
                float4 v = xr[ch * 64 + l];
                f16x4 h;
                h[0] = (f16)v.x; h[1] = (f16)v.y; h[2] = (f16)v.z; h[3] = (f16)v.w;
                *(f16x4*)(Xh + (size_t)row * 1024 + (ch * 64 + l) * 4) = h;
                s += v.x * v.x + v.y * v.y + v.z * v.z + v.w * v.w;
            }
#pragma unroll
            for (int off = 32; off >= 1; off >>= 1) s += __shfl_xor(s, off, 64);
            if (l == 0) nrm2[row] = s;
        }
        return;
    }

    // --- sim block: basis states t0, t0+1 ---
    const int sb = bid;
    const int t0 = (sb & 7) * 128 + (sb >> 3) * 2;   // XCD-group swizzle

    for (int i = threadIdx.x; i < 1024; i += 256) {
        st[0][i] = make_float2((i == t0) ? 1.f : 0.f, 0.f);
        st[1][i] = make_float2((i == t0 + 1) ? 1.f : 0.f, 0.f);
    }
    __syncthreads();

    for (int g = 0; g < 27; g++) {
        const int2 p = gp[g];            // uniform -> s_load
        float2 m[16];
#pragma unroll
        for (int i = 0; i < 16; i++) m[i] = gm[g * 16 + i];   // uniform -> s_load
        const int p1 = p.x, p2 = p.y;
        const int lo = min(p1, p2), hi = max(p1, p2);
        const int q = threadIdx.x;
        const int m1 = (1 << lo) - 1;
        int tt = (q & m1) | ((q & ~m1) << 1);
        const int m2m = (1 << hi) - 1;
        const int i0 = (tt & m2m) | ((tt & ~m2m) << 1);
        int idx[4];
        for (int ga = 0; ga < 2; ga++)
            for (int gb = 0; gb < 2; gb++)
                idx[2 * ga + gb] = i0 | (ga << p1) | (gb << p2);
#pragma unroll
        for (int c = 0; c < 2; c++) {
            float2 v[4];
#pragma unroll
            for (int i = 0; i < 4; i++) v[i] = st[c][idx[i]];
#pragma unroll
            for (int i = 0; i < 4; i++) {
                float2 s = make_float2(0.f, 0.f);
#pragma unroll
                for (int j = 0; j < 4; j++) s = cadd(s, cmul(m[i * 4 + j], v[j]));
                st[c][idx[i]] = s;       // in-place: quad is thread-private
            }
        }
        __syncthreads();
    }

    // --- f16x2 store into BTh [n'][1024] at columns t0, t0+1 ---
    // n' < 768 = Re, else Im; n' % 768 = grp*256 + pos,
    // grp: (b9,b7)=(1,0)->0, (1,1)->1, (0,1)->2; pos = bit8(s)*128 | (s&127).
    for (int s = threadIdx.x; s < 1024; s += 256) {
        const int b9 = (s >> 9) & 1, b7 = (s >> 7) & 1;
        if (b9 | b7) {
            const int grp = b9 ? b7 : 2;
            const int pos = (((s >> 8) & 1) << 7) | (s & 127);
            const int np = grp * 256 + pos;
            f16x2 re, im;
#pragma unroll
            for (int c = 0; c < 2; c++) {
                re[c] = (f16)st[c][s].x;
                im[c] = (f16)st[c][s].y;
            }
            *(f16x2*)(BTh + (size_t)np * 1024 + t0) = re;
            *(f16x2*)(BTh + (size_t)(np + 768) * 1024 + t0) = im;
        }
    }
}

__device__ __forceinline__ void glds16(const void* g, void* l) {
    __builtin_amdgcn_global_load_lds(
        (const __attribute__((address_space(1))) void*)g,
        (__attribute__((address_space(3))) void*)l, 16, 0, 0);
}

// Y = Xh @ BTh^T fused with masked-square reduction and FINAL output:
// atomicAdd(out[row][k], -2 * c_k / nrm2[row]) on top of prep's out=1 init.
// A: 16384x1024 f16. Bt: 1536x1024 f16 (N x K). 128x128 tile, BK=32, 4 waves,
// each wave 64x64 via 4x4 of 16x16x32 MFMA. LDS XOR chunk-swizzle (R2-verified).
__global__ __launch_bounds__(256) void gemm_mfma(const f16* __restrict__ A,
                                                 const f16* __restrict__ Bt,
                                                 const float* __restrict__ nrm2,
                                                 float* __restrict__ out) {
    __shared__ char Ash[8192];
    __shared__ char Bsh[8192];
    const int tid = threadIdx.x;
    const int l = tid & 63, w = tid >> 6;
    const int wr = w >> 1, wc = w & 1;
    const int row0 = blockIdx.x * 128, col0 = blockIdx.y * 128;

    const int mrow = l >> 2;
    const int kc = (l & 3) ^ ((l >> 3) & 3);
    const f16* aS0 = A  + (size_t)(row0 + 32 * w + mrow) * 1024 + kc * 8;
    const f16* aS1 = aS0 + 16 * 1024;
    const f16* bS0 = Bt + (size_t)(col0 + 32 * w + mrow) * 1024 + kc * 8;
    const f16* bS1 = bS0 + 16 * 1024;
    char* aD0 = Ash + 2048 * w;
    char* aD1 = aD0 + 1024;
    char* bD0 = Bsh + 2048 * w;
    char* bD1 = bD0 + 1024;

    int aOff[4], bOff[4];
#pragma unroll
    for (int i = 0; i < 4; i++) {
        int m = wr * 64 + i * 16 + (l & 15);
        aOff[i] = m * 64 + (((l >> 4) ^ ((m >> 1) & 3)) << 4);
        int n = wc * 64 + i * 16 + (l & 15);
        bOff[i] = n * 64 + (((l >> 4) ^ ((n >> 1) & 3)) << 4);
    }

    f32x4 acc[4][4];
    const f32x4 z = {0.f, 0.f, 0.f, 0.f};
#pragma unroll
    for (int i = 0; i < 4; i++)
#pragma unroll
        for (int j = 0; j < 4; j++) acc[i][j] = z;

    for (int k0 = 0; k0 < 1024; k0 += 32) {
        glds16(aS0 + k0, aD0);
        glds16(aS1 + k0, aD1);
        glds16(bS0 + k0, bD0);
        glds16(bS1 + k0, bD1);
        __syncthreads();
        f16x8 af[4], bf[4];
#pragma unroll
        for (int i = 0; i < 4; i++) {
            af[i] = *(const f16x8*)(Ash + aOff[i]);
            bf[i] = *(const f16x8*)(Bsh + bOff[i]);
        }
#pragma unroll
        for (int mi = 0; mi < 4; mi++)
#pragma unroll
            for (int ni = 0; ni < 4; ni++)
                acc[mi][ni] = __builtin_amdgcn_mfma_f32_16x16x32_f16(
                    af[mi], bf[ni], acc[mi][ni], 0, 0, 0);
        __syncthreads();
    }

    // fused epilogue: group-weighted squares, reduce over the 16 col-lanes,
    // then atomic-accumulate the final contribution into out.
    float c0[4][4], c1[4][4];   // [mi][reg-row]
#pragma unroll
    for (int mi = 0; mi < 4; mi++)
#pragma unroll
        for (int rr = 0; rr < 4; rr++) { c0[mi][rr] = 0.f; c1[mi][rr] = 0.f; }
#pragma unroll
    for (int ni = 0; ni < 4; ni++) {
        const int n_glob = col0 + wc * 64 + ni * 16 + (l & 15);
        const int nm = (n_glob >= 768) ? n_glob - 768 : n_glob;
        const int grp = nm >> 8;                       // 0: b9 only, 1: both, 2: b7 only
        const float w0 = (grp <= 1) ? 1.f : 0.f;
        const float w1 = (grp >= 1) ? 1.f : 0.f;
#pragma unroll
        for (int mi = 0; mi < 4; mi++)
#pragma unroll
            for (int rr = 0; rr < 4; rr++) {
                const float y = acc[mi][ni][rr];
                const float y2 = y * y;
                c0[mi][rr] += w0 * y2;
                c1[mi][rr] += w1 * y2;
            }
    }
#pragma unroll
    for (int off = 1; off < 16; off <<= 1)
#pragma unroll
        for (int mi = 0; mi < 4; mi++)
#pragma unroll
            for (int rr = 0; rr < 4; rr++) {
                c0[mi][rr] += __shfl_xor(c0[mi][rr], off, 64);
                c1[mi][rr] += __shfl_xor(c1[mi][rr], off, 64);
            }
    if ((l & 15) == 0) {
        const int q = l >> 4;
#pragma unroll
        for (int mi = 0; mi < 4; mi++)
#pragma unroll
            for (int rr = 0; rr < 4; rr++) {
                const int row = row0 + wr * 64 + mi * 16 + q * 4 + rr;
                const float inv = -2.0f / nrm2[row];
                atomicAdd(&out[row * 2 + 0], c0[mi][rr] * inv);
                atomicAdd(&out[row * 2 + 1], c1[mi][rr] * inv);
            }
    }
}

extern "C" void kernel_launch(void* const* d_in, const int* in_sizes, int n_in,
                              void* d_out, int out_size, void* d_ws, size_t ws_size,
                              hipStream_t stream) {
    const float* x   = (const float*)d_in[0];   // 16384 x 1024
    const float* wc1 = (const float*)d_in[1];   // 10 x 15
    const float* wc2 = (const float*)d_in[2];   // 4 x 15
    const float* wp1 = (const float*)d_in[3];   // 5 x 2
    const float* wp2 = (const float*)d_in[4];   // 2 x 2
    const float* wfc = (const float*)d_in[5];   // 3
    float* out = (float*)d_out;                 // 16384 x 2

    uintptr_t wsp = (uintptr_t)d_ws;
    int2*   gp     = (int2*)wsp;                                   // 216 B
    float2* gm     = (float2*)(wsp + 1024);                        // 3.4 KB
    f16*    BTh    = (f16*)(wsp + 8192);                           // 3 MB (1536x1024)
    f16*    Xh     = (f16*)(wsp + 8192 + (3u << 20));              // 32 MB
    float*  nrm2   = (float*)(wsp + 8192 + (35u << 20));           // 64 KB

    build_gates<<<1, 128, 0, stream>>>(wc1, wc2, wp1, wp2, wfc, gp, gm);
    prep<<<SIM_BLOCKS + NORM_BLOCKS, 256, 0, stream>>>(x, gp, gm, nrm2, Xh, BTh, out);
    gemm_mfma<<<dim3(128, 12), 256, 0, stream>>>(Xh, BTh, nrm2, out);
}

// Round 10
// 211.255 us; speedup vs baseline: 1.0761x; 1.0214x over previous
//
#include <hip/hip_runtime.h>

// ---------------------------------------------------------------------------
// QCNN classifier: whole circuit == fixed 1024x1024 unitary U(weights).
// out[b,0] = 1 - 2*sum_{bit9(s)=1} |(U x_b)_s|^2 / ||x_b||^2   (qubit 0)
// out[b,1] = 1 - 2*sum_{bit7(s)=1} |(U x_b)_s|^2 / ||x_b||^2   (qubit 2)
// Only 768 of 1024 states needed (bit9|bit7) -> N=1536 GEMM (51.5 GF).
// R10: gemm BK=64 — 16 outer iters (vs 32), 2 barrier-free 32-k MFMA
// sub-steps per iter -> half the vmcnt-drain barriers (the measured ~55%
// stall). 8-chunk XOR swizzle (phys = c_log ^ (row&7)). 3 blocks/CU kept
// (LDS 32KB, regs ~144/wave incl. 64 AGPR). grid 1536 = 2 exact rounds.
// ---------------------------------------------------------------------------

typedef _Float16 f16;
typedef f16 f16x8 __attribute__((ext_vector_type(8)));
typedef f16 f16x4 __attribute__((ext_vector_type(4)));
typedef f16 f16x2 __attribute__((ext_vector_type(2)));
typedef float f32x4 __attribute__((ext_vector_type(4)));

__device__ inline float2 cmul(float2 a, float2 b) {
    return make_float2(a.x * b.x - a.y * b.y, a.x * b.y + a.y * b.x);
}
__device__ inline float2 cadd(float2 a, float2 b) {
    return make_float2(a.x + b.x, a.y + b.y);
}

struct M2 { float2 m[4]; };

__device__ inline M2 m2_u3(float t, float p, float d) {
    float c = cosf(0.5f * t), s = sinf(0.5f * t);
    float2 ep = make_float2(cosf(p), sinf(p));
    float2 ed = make_float2(cosf(d), sinf(d));
    M2 U;
    U.m[0] = make_float2(c, 0.f);
    U.m[1] = make_float2(-ed.x * s, -ed.y * s);
    U.m[2] = make_float2(ep.x * s, ep.y * s);
    float2 epd = cmul(ep, ed);
    U.m[3] = make_float2(epd.x * c, epd.y * c);
    return U;
}
__device__ inline M2 m2_ry(float t) {
    float c = cosf(0.5f * t), s = sinf(0.5f * t);
    M2 U;
    U.m[0] = make_float2(c, 0.f);  U.m[1] = make_float2(-s, 0.f);
    U.m[2] = make_float2(s, 0.f);  U.m[3] = make_float2(c, 0.f);
    return U;
}
__device__ inline M2 m2_rz(float t) {
    float c = cosf(0.5f * t), s = sinf(0.5f * t);
    M2 U;
    U.m[0] = make_float2(c, -s); U.m[1] = make_float2(0.f, 0.f);
    U.m[2] = make_float2(0.f, 0.f); U.m[3] = make_float2(c, s);
    return U;
}
__device__ inline M2 m2_rx(float t) {
    float c = cosf(0.5f * t), s = sinf(0.5f * t);
    M2 U;
    U.m[0] = make_float2(c, 0.f);   U.m[1] = make_float2(0.f, -s);
    U.m[2] = make_float2(0.f, -s);  U.m[3] = make_float2(c, 0.f);
    return U;
}

// apply 2x2 complex matrix to an amplitude pair
__device__ inline void ap2x2(float2& x, float2& y, const M2& U) {
    float2 nx = cadd(cmul(U.m[0], x), cmul(U.m[1], y));
    float2 ny = cadd(cmul(U.m[2], x), cmul(U.m[3], y));
    x = nx; y = ny;
}
// 4-vector indexed by (2a+b). apA: U on a (pairs 0-2, 1-3). apB: U on b (0-1, 2-3).
__device__ inline void apA(float2 v[4], const M2& U) { ap2x2(v[0], v[2], U); ap2x2(v[1], v[3], U); }
__device__ inline void apB(float2 v[4], const M2& U) { ap2x2(v[0], v[1], U); ap2x2(v[2], v[3], U); }
__device__ inline void swapv(float2& a, float2& b) { float2 t = a; a = b; b = t; }

// column c of the conv block: propagate e_c through the 10 elementary steps
__device__ inline void conv_col(const float* w, float2 v[4]) {
    apA(v, m2_u3(w[0], w[1], w[2]));
    apB(v, m2_u3(w[3], w[4], w[5]));
    swapv(v[2], v[3]);                    // cnot (control=a)
    apA(v, m2_ry(w[6]));
    apB(v, m2_rz(w[7]));
    swapv(v[1], v[3]);                    // cnot (control=b)
    apA(v, m2_ry(w[8]));
    swapv(v[2], v[3]);                    // cnot (control=a)
    apA(v, m2_u3(w[9], w[10], w[11]));
    apB(v, m2_u3(w[12], w[13], w[14]));
}
__device__ inline void pool_col(const float* p, float2 v[4]) {
    {   // crz(p0): diag(1,1,e^{-ip0/2},e^{+ip0/2})
        float c = cosf(0.5f * p[0]), s = sinf(0.5f * p[0]);
        v[2] = cmul(v[2], make_float2(c, -s));
        v[3] = cmul(v[3], make_float2(c, s));
    }
    swapv(v[0], v[2]); swapv(v[1], v[3]); // X on a
    {   // crx(p1) on (v2,v3)
        M2 U = m2_rx(p[1]);
        ap2x2(v[2], v[3], U);
    }
}

// One thread per (gate, column). Writes gp (bit positions) + gm (matrices)
// to GLOBAL memory so the sim can read them with uniform s_loads.
__global__ void build_gates(const float* wc1, const float* wc2,
                            const float* wp1, const float* wp2,
                            const float* wfc, int2* gp, float2* gm) {
    const int t = threadIdx.x;
    const int n = t >> 2, c = t & 3;
    if (blockIdx.x != 0 || n >= 27) return;

    float2 v[4];
    for (int i = 0; i < 4; i++) v[i] = make_float2(0.f, 0.f);
    v[c] = make_float2(1.f, 0.f);

    int a, b;
    if (n < 5)        { int i = 2*n;       a = i;   b = i+1; conv_col(wc1 + 15*i, v); }
    else if (n < 9)   { int i = 2*(n-5)+1; a = i;   b = i+1; conv_col(wc1 + 15*i, v); }
    else if (n == 9)  { a = 0; b = 9;      conv_col(wc1 + 105, v); }
    else if (n < 15)  { int idx = n-10, i = 2*idx; a = i+1; b = i; pool_col(wp1 + 2*idx, v); }
    else if (n < 19)  { int idx = n-15, i = 2*idx; a = i; b = i+2; conv_col(wc2 + 15*idx, v); }
    else if (n == 19) { a = 2; b = 0;      pool_col(wp2 + 0, v); }
    else if (n == 20) { a = 6; b = 4;      pool_col(wp2 + 2, v); }
    else if (n <= 23) { // CNOTs (control = a)
        a = (n == 21) ? 0 : (n == 22) ? 2 : 4;
        b = (n == 23) ? 0 : 4;
        swapv(v[2], v[3]);
    } else {            // RX on qubit a
        a = (n == 24) ? 0 : (n == 25) ? 2 : 4;
        b = a + 1;
        apA(v, m2_rx(wfc[n - 24]));
    }
    if (c == 0) gp[n] = make_int2(9 - a, 9 - b);   // qubit q -> bit (9-q)
    for (int i = 0; i < 4; i++) gm[n * 16 + i * 4 + c] = v[i];
}

#define SIM_BLOCKS 512     // 2 columns each, dispatched FIRST
#define NORM_BLOCKS 2048   // 8 rows/block

// Fused prep. Blocks [0, SIM_BLOCKS): 2 U-columns simulated in LDS (in-place,
// 1 barrier/gate; gate matrices via uniform s_load from gm), f16x2 stores into
// BTh [n'][1024 k] with XCD-group t-swizzle (XCD x owns t range [128x,128x+128)).
// Blocks [SIM_BLOCKS, +NORM_BLOCKS): row norms + fp32->f16 X conversion
// (wave-per-row, no LDS use) + out = 1.0 init for its 8 rows.
__global__ __launch_bounds__(256) void prep(const float* __restrict__ X,
                                            const int2* __restrict__ gp,
                                            const float2* __restrict__ gm,
                                            float* __restrict__ nrm2,
                                            f16* __restrict__ Xh,
                                            f16* __restrict__ BTh,
                                            float* __restrict__ out) {
    __shared__ float2 st[2][1025];   // [col][state], +1 pad
    const int bid = blockIdx.x;

    if (bid >= SIM_BLOCKS) {
        const int nb = bid - SIM_BLOCKS;
        const int w = threadIdx.x >> 6, l = threadIdx.x & 63;
        if (threadIdx.x < 16) out[nb * 16 + threadIdx.x] = 1.0f;
#pragma unroll
        for (int r = 0; r < 2; r++) {
            const int row = nb * 8 + w * 2 + r;
            const float4* xr = (const float4*)(X + (size_t)row * 1024);
            float s = 0.f;
#pragma unroll
            for (int ch = 0; ch < 4; ch++) {
                float4 v = xr[ch * 64 + l];
                f16x4 h;
                h[0] = (f16)v.x; h[1] = (f16)v.y; h[2] = (f16)v.z; h[3] = (f16)v.w;
                *(f16x4*)(Xh + (size_t)row * 1024 + (ch * 64 + l) * 4) = h;
                s += v.x * v.x + v.y * v.y + v.z * v.z + v.w * v.w;
            }
#pragma unroll
            for (int off = 32; off >= 1; off >>= 1) s += __shfl_xor(s, off, 64);
            if (l == 0) nrm2[row] = s;
        }
        return;
    }

    // --- sim block: basis states t0, t0+1 ---
    const int sb = bid;
    const int t0 = (sb & 7) * 128 + (sb >> 3) * 2;   // XCD-group swizzle

    for (int i = threadIdx.x; i < 1024; i += 256) {
        st[0][i] = make_float2((i == t0) ? 1.f : 0.f, 0.f);
        st[1][i] = make_float2((i == t0 + 1) ? 1.f : 0.f, 0.f);
    }
    __syncthreads();

    for (int g = 0; g < 27; g++) {
        const int2 p = gp[g];            // uniform -> s_load
        float2 m[16];
#pragma unroll
        for (int i = 0; i < 16; i++) m[i] = gm[g * 16 + i];   // uniform -> s_load
        const int p1 = p.x, p2 = p.y;
        const int lo = min(p1, p2), hi = max(p1, p2);
        const int q = threadIdx.x;
        const int m1 = (1 << lo) - 1;
        int tt = (q & m1) | ((q & ~m1) << 1);
        const int m2m = (1 << hi) - 1;
        const int i0 = (tt & m2m) | ((tt & ~m2m) << 1);
        int idx[4];
        for (int ga = 0; ga < 2; ga++)
            for (int gb = 0; gb < 2; gb++)
                idx[2 * ga + gb] = i0 | (ga << p1) | (gb << p2);
#pragma unroll
        for (int c = 0; c < 2; c++) {
            float2 v[4];
#pragma unroll
            for (int i = 0; i < 4; i++) v[i] = st[c][idx[i]];
#pragma unroll
            for (int i = 0; i < 4; i++) {
                float2 s = make_float2(0.f, 0.f);
#pragma unroll
                for (int j = 0; j < 4; j++) s = cadd(s, cmul(m[i * 4 + j], v[j]));
                st[c][idx[i]] = s;       // in-place: quad is thread-private
            }
        }
        __syncthreads();
    }

    // --- f16x2 store into BTh [n'][1024] at columns t0, t0+1 ---
    // n' < 768 = Re, else Im; n' % 768 = grp*256 + pos,
    // grp: (b9,b7)=(1,0)->0, (1,1)->1, (0,1)->2; pos = bit8(s)*128 | (s&127).
    for (int s = threadIdx.x; s < 1024; s += 256) {
        const int b9 = (s >> 9) & 1, b7 = (s >> 7) & 1;
        if (b9 | b7) {
            const int grp = b9 ? b7 : 2;
            const int pos = (((s >> 8) & 1) << 7) | (s & 127);
            const int np = grp * 256 + pos;
            f16x2 re, im;
#pragma unroll
            for (int c = 0; c < 2; c++) {
                re[c] = (f16)st[c][s].x;
                im[c] = (f16)st[c][s].y;
            }
            *(f16x2*)(BTh + (size_t)np * 1024 + t0) = re;
            *(f16x2*)(BTh + (size_t)(np + 768) * 1024 + t0) = im;
        }
    }
}

__device__ __forceinline__ void glds16(const void* g, void* l) {
    __builtin_amdgcn_global_load_lds(
        (const __attribute__((address_space(1))) void*)g,
        (__attribute__((address_space(3))) void*)l, 16, 0, 0);
}

// Y = Xh @ BTh^T fused with masked-square reduction and final output:
// atomicAdd(out[row][k], -2 * c_k / nrm2[row]) on top of prep's out=1 init.
// A: 16384x1024 f16. Bt: 1536x1024 f16 (N x K). 128x128 tile, BK=64 (16 outer
// iters; 2 barrier-free 32-k MFMA sub-steps per iter), 4 waves, each wave
// 64x64 via 4x4 of 16x16x32 MFMA per sub-step.
// LDS tile: 128 rows x 128 B (8 x 16B chunks/row), phys_chunk = c_log ^ (row&7)
// -> glds dest stays lane-contiguous AND frag ds_read_b128 <=2-way conflict.
__global__ __launch_bounds__(256) void gemm_mfma(const f16* __restrict__ A,
                                                 const f16* __restrict__ Bt,
                                                 const float* __restrict__ nrm2,
                                                 float* __restrict__ out) {
    __shared__ char Ash[16384];
    __shared__ char Bsh[16384];
    const int tid = threadIdx.x;
    const int l = tid & 63, w = tid >> 6;
    const int wr = w >> 1, wc = w & 1;
    const int row0 = blockIdx.x * 128, col0 = blockIdx.y * 128;

    // staging: wave w stages rows [32w, 32w+32) of A and B in 4 glds each
    // (8 rows per glds; lane l -> row +(l>>3), phys chunk l&7).
    // c_log = (l&7) ^ (row&7) = (l&7) ^ ((l>>3)&7)  (32w+8g ≡ 0 mod 8)
    const int srow = l >> 3;                       // 0..7
    const int kc = (l & 7) ^ (srow & 7);           // logical chunk (8 f16)
    const f16* aS = A  + (size_t)(row0 + 32 * w + srow) * 1024 + kc * 8;
    const f16* bS = Bt + (size_t)(col0 + 32 * w + srow) * 1024 + kc * 8;
    char* aD = Ash + (32 * w) * 128;
    char* bD = Bsh + (32 * w) * 128;

    // fragment ds_read offsets: m = wr*64 + i*16 + (l&15), k-half h:
    // c_log = (l>>4) + 4h, phys = c_log ^ (m&7) = c_log ^ (l&7)
    int aOff[4][2], bOff[4][2];
#pragma unroll
    for (int i = 0; i < 4; i++)
#pragma unroll
        for (int h = 0; h < 2; h++) {
            const int cphys = (((l >> 4) + 4 * h) ^ (l & 7));
            aOff[i][h] = (wr * 64 + i * 16 + (l & 15)) * 128 + cphys * 16;
            bOff[i][h] = (wc * 64 + i * 16 + (l & 15)) * 128 + cphys * 16;
        }

    f32x4 acc[4][4];
    const f32x4 z = {0.f, 0.f, 0.f, 0.f};
#pragma unroll
    for (int i = 0; i < 4; i++)
#pragma unroll
        for (int j = 0; j < 4; j++) acc[i][j] = z;

    for (int k0 = 0; k0 < 1024; k0 += 64) {
#pragma unroll
        for (int g = 0; g < 4; g++) {
            glds16(aS + k0 + g * 8 * 1024, aD + g * 1024);
            glds16(bS + k0 + g * 8 * 1024, bD + g * 1024);
        }
        __syncthreads();
#pragma unroll
        for (int h = 0; h < 2; h++) {
            f16x8 af[4], bf[4];
#pragma unroll
            for (int i = 0; i < 4; i++) {
                af[i] = *(const f16x8*)(Ash + aOff[i][h]);
                bf[i] = *(const f16x8*)(Bsh + bOff[i][h]);
            }
#pragma unroll
            for (int mi = 0; mi < 4; mi++)
#pragma unroll
                for (int ni = 0; ni < 4; ni++)
                    acc[mi][ni] = __builtin_amdgcn_mfma_f32_16x16x32_f16(
                        af[mi], bf[ni], acc[mi][ni], 0, 0, 0);
        }
        __syncthreads();
    }

    // fused epilogue: group-weighted squares, reduce over the 16 col-lanes,
    // then atomic-accumulate the final contribution into out.
    float c0[4][4], c1[4][4];   // [mi][reg-row]
#pragma unroll
    for (int mi = 0; mi < 4; mi++)
#pragma unroll
        for (int rr = 0; rr < 4; rr++) { c0[mi][rr] = 0.f; c1[mi][rr] = 0.f; }
#pragma unroll
    for (int ni = 0; ni < 4; ni++) {
        const int n_glob = col0 + wc * 64 + ni * 16 + (l & 15);
        const int nm = (n_glob >= 768) ? n_glob - 768 : n_glob;
        const int grp = nm >> 8;                       // 0: b9 only, 1: both, 2: b7 only
        const float w0 = (grp <= 1) ? 1.f : 0.f;
        const float w1 = (grp >= 1) ? 1.f : 0.f;
#pragma unroll
        for (int mi = 0; mi < 4; mi++)
#pragma unroll
            for (int rr = 0; rr < 4; rr++) {
                const float y = acc[mi][ni][rr];
                const float y2 = y * y;
                c0[mi][rr] += w0 * y2;
                c1[mi][rr] += w1 * y2;
            }
    }
#pragma unroll
    for (int off = 1; off < 16; off <<= 1)
#pragma unroll
        for (int mi = 0; mi < 4; mi++)
#pragma unroll
            for (int rr = 0; rr < 4; rr++) {
                c0[mi][rr] += __shfl_xor(c0[mi][rr], off, 64);
                c1[mi][rr] += __shfl_xor(c1[mi][rr], off, 64);
            }
    if ((l & 15) == 0) {
        const int q = l >> 4;
#pragma unroll
        for (int mi = 0; mi < 4; mi++)
#pragma unroll
            for (int rr = 0; rr < 4; rr++) {
                const int row = row0 + wr * 64 + mi * 16 + q * 4 + rr;
                const float inv = -2.0f / nrm2[row];
                atomicAdd(&out[row * 2 + 0], c0[mi][rr] * inv);
                atomicAdd(&out[row * 2 + 1], c1[mi][rr] * inv);
            }
    }
}

extern "C" void kernel_launch(void* const* d_in, const int* in_sizes, int n_in,
                              void* d_out, int out_size, void* d_ws, size_t ws_size,
                              hipStream_t stream) {
    const float* x   = (const float*)d_in[0];   // 16384 x 1024
    const float* wc1 = (const float*)d_in[1];   // 10 x 15
    const float* wc2 = (const float*)d_in[2];   // 4 x 15
    const float* wp1 = (const float*)d_in[3];   // 5 x 2
    const float* wp2 = (const float*)d_in[4];   // 2 x 2
    const float* wfc = (const float*)d_in[5];   // 3
    float* out = (float*)d_out;                 // 16384 x 2

    uintptr_t wsp = (uintptr_t)d_ws;
    int2*   gp     = (int2*)wsp;                                   // 216 B
    float2* gm     = (float2*)(wsp + 1024);                        // 3.4 KB
    f16*    BTh    = (f16*)(wsp + 8192);                           // 3 MB (1536x1024)
    f16*    Xh     = (f16*)(wsp + 8192 + (3u << 20));              // 32 MB
    float*  nrm2   = (float*)(wsp + 8192 + (35u << 20));           // 64 KB

    build_gates<<<1, 128, 0, stream>>>(wc1, wc2, wp1, wp2, wfc, gp, gm);
    prep<<<SIM_BLOCKS + NORM_BLOCKS, 256, 0, stream>>>(x, gp, gm, nrm2, Xh, BTh, out);
    gemm_mfma<<<dim3(128, 12), 256, 0, stream>>>(Xh, BTh, nrm2, out);
}